// Round 1
// baseline (600.764 us; speedup 1.0000x reference)
//
#include <hip/hip_runtime.h>
#include <math.h>

#define BN 16384   // B*N rows
#define NCOL 4096
#define CDIM 256
#define DKDIM 64
#define SCALE 0.125f   // DK^-0.5

// ---------------- Kernel 1: Q = x Wq, K = x Wk ----------------
// Block: 256 threads (tx=d-group 0..15, ty=row-group 0..15), 64 rows/block.
// x staged in LDS (read from HBM exactly once); W streamed from L2 (64 KB, hot).
__global__ __launch_bounds__(256) void qk_gemm(const float* __restrict__ x,
                                               const float* __restrict__ Wq,
                                               const float* __restrict__ Wk,
                                               float* __restrict__ Qout,
                                               float* __restrict__ Kout) {
  __shared__ float xs[64][260];   // +4 pad: compute reads land on distinct banks
  const int rb = blockIdx.x;      // 256 row-blocks of 64 rows
  const float* __restrict__ W = blockIdx.y ? Wk : Wq;
  float* __restrict__ Out = blockIdx.y ? Kout : Qout;
  const int t  = threadIdx.x;
  const int tx = t & 15;
  const int ty = t >> 4;

  // stage x rows: 64 x 256 floats = 4096 float4, coalesced
  {
    const float4* xg = (const float4*)(x + (size_t)rb * 64 * CDIM);
    #pragma unroll
    for (int i = 0; i < 16; ++i) {
      int g = i * 256 + t;
      int row = g >> 6;
      int cp = g & 63;
      float4 v = xg[g];
      *(float4*)&xs[row][cp * 4] = v;
    }
  }
  __syncthreads();

  float acc[4][4] = {};
  #pragma unroll 2
  for (int c = 0; c < CDIM; c += 4) {
    float4 xf[4], wf[4];
    #pragma unroll
    for (int r = 0; r < 4; ++r) xf[r] = *(const float4*)&xs[ty * 4 + r][c];
    #pragma unroll
    for (int j = 0; j < 4; ++j) wf[j] = *(const float4*)&W[(c + j) * DKDIM + tx * 4];
    #pragma unroll
    for (int r = 0; r < 4; ++r) {
      const float xv[4] = {xf[r].x, xf[r].y, xf[r].z, xf[r].w};
      #pragma unroll
      for (int j = 0; j < 4; ++j) {
        acc[r][0] = fmaf(xv[j], wf[j].x, acc[r][0]);
        acc[r][1] = fmaf(xv[j], wf[j].y, acc[r][1]);
        acc[r][2] = fmaf(xv[j], wf[j].z, acc[r][2]);
        acc[r][3] = fmaf(xv[j], wf[j].w, acc[r][3]);
      }
    }
  }
  #pragma unroll
  for (int r = 0; r < 4; ++r) {
    float4 o = {acc[r][0], acc[r][1], acc[r][2], acc[r][3]};
    *(float4*)&Out[((size_t)rb * 64 + ty * 4 + r) * DKDIM + tx * 4] = o;
  }
}

// ---------------- Kernel 2: fused S = Q K^T + per-row top-8 ----------------
// Grid (256 rowblocks, 2 col-chunks). Block 256 threads; 64 rows x 2048 cols.
// Also zero-fills its 64x2048 output region (overlaps with compute).
__global__ __launch_bounds__(256, 2) void s_topk(const float* __restrict__ Q,
                                                 const float* __restrict__ Kmat,
                                                 float* __restrict__ out,
                                                 float* __restrict__ wsv,
                                                 int* __restrict__ wsi) {
  union SMem {
    struct { float qs[16][65][4]; float ks[16][129][4]; } a;  // float4-grouped + pad
    struct { float cv[64][129]; int ci[64][129]; } b;         // candidate merge
  };
  __shared__ SMem sm;

  const int rb = blockIdx.x;           // 0..255
  const int chunk = blockIdx.y;        // 0..1
  const int t  = threadIdx.x;
  const int tx = t & 15;
  const int ty = t >> 4;
  const int b  = rb >> 6;              // batch (64 rowblocks per batch)
  const size_t rowbase = (size_t)rb * 64;
  const int colbase = chunk * 2048;
  const float* __restrict__ Kb = Kmat + ((size_t)b * NCOL + colbase) * DKDIM;

  // 1) zero-fill my output region (fire-and-forget stores, overlap with compute)
  {
    float4 z = {0.f, 0.f, 0.f, 0.f};
    float4* o4 = (float4*)(out + rowbase * NCOL + colbase);
    #pragma unroll 4
    for (int i = 0; i < 128; ++i) {
      int g = i * 256 + t;             // 0..32767 (64 rows x 512 f4)
      int row = g >> 9;
      int cp = g & 511;
      o4[(size_t)row * 1024 + cp] = z;
    }
  }

  // 2) stage Q tile: qs[dgroup][row][4]
  {
    const float4* qg = (const float4*)(Q + rowbase * DKDIM);
    #pragma unroll
    for (int i = 0; i < 4; ++i) {
      int g = i * 256 + t;             // 0..1023
      int row = g >> 4;
      int dg = g & 15;
      float4 v = qg[g];
      *(float4*)&sm.a.qs[dg][row][0] = v;
    }
  }

  // per-thread top-8 state for 4 rows (cached min + position)
  float tv[4][8]; int ti[4][8]; float tmin[4]; int tmpos[4];
  #pragma unroll
  for (int r = 0; r < 4; ++r) {
    tmin[r] = -INFINITY; tmpos[r] = 0;
    #pragma unroll
    for (int j = 0; j < 8; ++j) { tv[r][j] = -INFINITY; ti[r][j] = 0; }
  }

  for (int kt = 0; kt < 16; ++kt) {
    __syncthreads();                   // protect ks from previous tile's reads
    {
      const float4* kg = (const float4*)(Kb + (size_t)kt * 128 * DKDIM);
      #pragma unroll
      for (int i = 0; i < 8; ++i) {
        int g = i * 256 + t;           // 0..2047
        int col = g >> 4;
        int dg = g & 15;
        float4 v = kg[g];
        *(float4*)&sm.a.ks[dg][col][0] = v;
      }
    }
    __syncthreads();

    float acc[4][8] = {};
    #pragma unroll 4
    for (int g = 0; g < 16; ++g) {
      float4 qf[4], kf[8];
      #pragma unroll
      for (int r = 0; r < 4; ++r) qf[r] = *(const float4*)&sm.a.qs[g][ty * 4 + r][0];
      #pragma unroll
      for (int j = 0; j < 8; ++j) kf[j] = *(const float4*)&sm.a.ks[g][tx + 16 * j][0];
      #pragma unroll
      for (int r = 0; r < 4; ++r) {
        #pragma unroll
        for (int j = 0; j < 8; ++j) {
          acc[r][j] = fmaf(qf[r].x, kf[j].x, acc[r][j]);
          acc[r][j] = fmaf(qf[r].y, kf[j].y, acc[r][j]);
          acc[r][j] = fmaf(qf[r].z, kf[j].z, acc[r][j]);
          acc[r][j] = fmaf(qf[r].w, kf[j].w, acc[r][j]);
        }
      }
    }

    // top-8 update (prune whole tile-row if its max can't beat current min)
    #pragma unroll
    for (int r = 0; r < 4; ++r) {
      float tmax = acc[r][0];
      #pragma unroll
      for (int j = 1; j < 8; ++j) tmax = fmaxf(tmax, acc[r][j]);
      if (tmax > tmin[r]) {
        #pragma unroll
        for (int j = 0; j < 8; ++j) {
          float v = acc[r][j];
          if (v > tmin[r]) {
            int col = colbase + kt * 128 + tx + 16 * j;
            int p = tmpos[r];
            #pragma unroll
            for (int q = 0; q < 8; ++q)
              if (q == p) { tv[r][q] = v; ti[r][q] = col; }
            float m = tv[r][0]; int mp = 0;
            #pragma unroll
            for (int q = 1; q < 8; ++q)
              if (tv[r][q] < m) { m = tv[r][q]; mp = q; }
            tmin[r] = m; tmpos[r] = mp;
          }
        }
      }
    }
  }

  __syncthreads();                     // done reading qs/ks; reuse LDS
  #pragma unroll
  for (int r = 0; r < 4; ++r) {
    #pragma unroll
    for (int j = 0; j < 8; ++j) {
      sm.b.cv[ty * 4 + r][tx * 8 + j] = tv[r][j];
      sm.b.ci[ty * 4 + r][tx * 8 + j] = ti[r][j];
    }
  }
  __syncthreads();

  // block-level merge: 128 candidates -> chunk-local top-8 per row
  if (t < 64) {
    int row = t;
    float rv[8]; int rid[8];
    #pragma unroll
    for (int j = 0; j < 8; ++j) { rv[j] = sm.b.cv[row][j]; rid[j] = sm.b.ci[row][j]; }
    float m = rv[0]; int mp = 0;
    #pragma unroll
    for (int q = 1; q < 8; ++q) if (rv[q] < m) { m = rv[q]; mp = q; }
    for (int c2 = 8; c2 < 128; ++c2) {
      float v = sm.b.cv[row][c2];
      if (v > m) {
        int col = sm.b.ci[row][c2];
        #pragma unroll
        for (int q = 0; q < 8; ++q) if (q == mp) { rv[q] = v; rid[q] = col; }
        m = rv[0]; mp = 0;
        #pragma unroll
        for (int q = 1; q < 8; ++q) if (rv[q] < m) { m = rv[q]; mp = q; }
      }
    }
    size_t rg = rowbase + row;
    #pragma unroll
    for (int j = 0; j < 8; ++j) {
      wsv[rg * 16 + chunk * 8 + j] = rv[j];
      wsi[rg * 16 + chunk * 8 + j] = rid[j];
    }
  }
}

// ---------------- Kernel 3: merge 2 chunks, softmax, scatter ----------------
__global__ __launch_bounds__(256) void merge_scatter(const float* __restrict__ wsv,
                                                     const int* __restrict__ wsi,
                                                     float* __restrict__ out) {
  int row = blockIdx.x * 256 + threadIdx.x;    // 0..16383
  float v[16]; int id[16];
  const float4* v4 = (const float4*)(wsv + (size_t)row * 16);
  const int4*   i4 = (const int4*)(wsi + (size_t)row * 16);
  #pragma unroll
  for (int i = 0; i < 4; ++i) {
    float4 a = v4[i]; v[4*i] = a.x; v[4*i+1] = a.y; v[4*i+2] = a.z; v[4*i+3] = a.w;
    int4   c = i4[i]; id[4*i] = c.x; id[4*i+1] = c.y; id[4*i+2] = c.z; id[4*i+3] = c.w;
  }
  float rv[8]; int rid[8];
  #pragma unroll
  for (int j = 0; j < 8; ++j) { rv[j] = v[j]; rid[j] = id[j]; }
  float m = rv[0]; int mp = 0;
  #pragma unroll
  for (int q = 1; q < 8; ++q) if (rv[q] < m) { m = rv[q]; mp = q; }
  #pragma unroll
  for (int c = 8; c < 16; ++c) {
    if (v[c] > m) {
      #pragma unroll
      for (int q = 0; q < 8; ++q) if (q == mp) { rv[q] = v[c]; rid[q] = id[c]; }
      m = rv[0]; mp = 0;
      #pragma unroll
      for (int q = 1; q < 8; ++q) if (rv[q] < m) { m = rv[q]; mp = q; }
    }
  }
  // softmax over the 8 kept entries (masked entries are exactly 0 in out)
  float vmax = rv[0];
  #pragma unroll
  for (int q = 1; q < 8; ++q) vmax = fmaxf(vmax, rv[q]);
  float e[8], s = 0.f;
  #pragma unroll
  for (int q = 0; q < 8; ++q) { e[q] = __expf((rv[q] - vmax) * SCALE); s += e[q]; }
  float inv = 1.f / s;
  float* orow = out + (size_t)row * NCOL;
  #pragma unroll
  for (int q = 0; q < 8; ++q) orow[rid[q]] = e[q] * inv;
}

extern "C" void kernel_launch(void* const* d_in, const int* in_sizes, int n_in,
                              void* d_out, int out_size, void* d_ws, size_t ws_size,
                              hipStream_t stream) {
  const float* x  = (const float*)d_in[0];
  const float* Wq = (const float*)d_in[1];
  const float* Wk = (const float*)d_in[2];
  float* out = (float*)d_out;

  char* ws = (char*)d_ws;
  float* Q   = (float*)ws;                                      // 4 MB
  float* K   = (float*)(ws + (size_t)BN * DKDIM * 4);           // 4 MB
  float* wsv = (float*)(ws + 2 * (size_t)BN * DKDIM * 4);       // 1 MB
  int*   wsi = (int*)  (ws + 2 * (size_t)BN * DKDIM * 4 + (size_t)BN * 16 * 4); // 1 MB

  qk_gemm<<<dim3(BN / 64, 2), 256, 0, stream>>>(x, Wq, Wk, Q, K);
  s_topk<<<dim3(BN / 64, 2), 256, 0, stream>>>(Q, K, out, wsv, wsi);
  merge_scatter<<<BN / 256, 256, 0, stream>>>(wsv, wsi, out);
}